// Round 16
// baseline (71.775 us; speedup 1.0000x reference)
//
#include <hip/hip_runtime.h>
#include <hip/hip_fp16.h>

// KnnExpansion: out[f, n] = sum_k alpha[i[n,k], f] * exp(-0.5 * d[n,k] / sigma^2)
// N=131072, K=32, M=65536, F=64.
//
// Structure (proven r7-r15): fused in-register quartile partition +
// 4-phase L2-resident gather + LDS-sourced entries + v_fma_mix consume.
// r15 (2 rows/instr) = 46us main, VGPR 16, no spill. This round: 4 rows
// per VMEM instr. global_load_dwordx2 (64 lanes x 8B = 512B) = FOUR f16
// rows; quarter-wave q covers entry p*8+t*4+q, 4 channels/lane. Per-wave
// VMEM gathers 128->64, consume VALU ~-40%. acc 32 regs (4ch x 8q).
// Spill defenses kept: per-lane LDS-sourced entries, sched_barrier(0)
// per (p,qi) (2-group hoist window), no min-wave clamp.

#define N_Q    131072
#define K_NB   32
#define F_CH   64
#define M_ROWS 65536

// ---- pre-pass: alpha f32 -> f16 (streaming, ~3us) ----
__global__ __launch_bounds__(256) void cvt_alpha_f16(
    const float* __restrict__ alpha, __half* __restrict__ a16)
{
    const int t = blockIdx.x * 256 + threadIdx.x;
    const float4 v0 = ((const float4*)alpha)[(size_t)t * 2 + 0];
    const float4 v1 = ((const float4*)alpha)[(size_t)t * 2 + 1];
    union { __half2 h2[4]; uint4 u; } pk;
    pk.h2[0] = __floats2half2_rn(v0.x, v0.y);
    pk.h2[1] = __floats2half2_rn(v0.z, v0.w);
    pk.h2[2] = __floats2half2_rn(v1.x, v1.y);
    pk.h2[3] = __floats2half2_rn(v1.z, v1.w);
    ((uint4*)a16)[t] = pk.u;
}

// ---- fused main: 4-rows-per-instr consume ----
__global__ __launch_bounds__(512) void knn_exp_row4(
    const float*  __restrict__ dmat,   // [N, 32]
    const int*    __restrict__ imat,   // [N, 32]
    const __half* __restrict__ a16,    // [65536, 64]
    const float*  __restrict__ sigma,  // [1]
    float*        __restrict__ out)    // [64, N]
{
    __shared__ float    tile[64][65];        // +1 pad
    __shared__ unsigned sortbuf[8][8][32];   // wave-local sort scratch

    const int lane = threadIdx.x & 63;
    const int wave = threadIdx.x >> 6;       // 8 waves x 8 queries
    const int n0   = blockIdx.x * 64;
    const bool hi  = (lane >= 32);
    const int  quarter = lane >> 4;          // which row of the 4-row group
    const int  l15 = lane & 15;
    const unsigned chan_off = (unsigned)l15 * 8u;  // 4 f16 channels per lane

    const float s = sigma[0];
    const float c = -0.5f / (s * s);

    // ---- batched prologue: 8 stream loads issued back-to-back (r10) ----
    const int nbase = n0 + wave * 8;
    const char* pbase = hi
        ? (const char*)&imat[(size_t)nbase * K_NB + (lane - 32)]
        : (const char*)&dmat[(size_t)nbase * K_NB + lane];
    unsigned raw[8];
    #pragma unroll
    for (int qi = 0; qi < 8; ++qi)
        raw[qi] = __builtin_nontemporal_load(
            (const unsigned*)(pbase + (size_t)qi * (K_NB * 4)));

    __builtin_amdgcn_sched_barrier(0);   // keep the batch; no sinking

    // ---- in-register quartile partition, pack (idx<<16 | f16(w)) ----
    #pragma unroll
    for (int qi = 0; qi < 8; ++qi) {
        const float wv = __expf(c * __uint_as_float(raw[qi])); // valid on lo
        const int   iv = (int)raw[qi];                         // valid on hi

        const unsigned hbits = (unsigned)__half_as_ushort(__float2half_rn(wv));
        const unsigned hb    = (unsigned)__shfl((int)hbits, lane & 31);

        const int quart = (iv >> 14) & 3;
        const unsigned long long m0 = __ballot(hi && quart == 0);
        const unsigned long long m1 = __ballot(hi && quart == 1);
        const unsigned long long m2 = __ballot(hi && quart == 2);
        const unsigned long long m3 = __ballot(hi && quart == 3);
        const int b1 = __popcll(m0);
        const int b2 = b1 + __popcll(m1);
        const int b3 = b2 + __popcll(m2);
        const unsigned long long mq =
            (quart == 0) ? m0 : (quart == 1) ? m1 : (quart == 2) ? m2 : m3;
        const int bq =
            (quart == 0) ? 0 : (quart == 1) ? b1 : (quart == 2) ? b2 : b3;
        const unsigned long long below = (1ull << lane) - 1ull;
        const int pos = bq + __popcll(mq & below);

        if (hi)
            sortbuf[wave][qi][pos] = ((unsigned)iv << 16) | (hb & 0xFFFFu);
    }
    // wave-local LDS RAW: same-wave ds ordering via lgkmcnt, no barrier.

    float acc[8][4];
    #pragma unroll
    for (int qi = 0; qi < 8; ++qi)
        #pragma unroll
        for (int cc = 0; cc < 4; ++cc) acc[qi][cc] = 0.0f;

    // ---- 4-phase consume: phase p ~= quartile p (2 MiB L2 slice).
    // Group t: entries e = p*8 + t*4 + quarter; the 16 lanes of each
    // quarter gather row(e) fully (16 x 8B = 128B); 4 channels/lane.
    #pragma unroll
    for (int p = 0; p < 4; ++p) {
        #pragma unroll
        for (int qi = 0; qi < 8; ++qi) {
            #pragma unroll
            for (int t = 0; t < 2; ++t) {
                const unsigned e = sortbuf[wave][qi][p * 8 + t * 4 + quarter];
                const unsigned off = ((e >> 16) << 7) + chan_off;
                const uint2 dat = *(const uint2*)((const char*)a16 + off);
                // acc[c] += f16(e.lo) * f16(dat.{x,y}.{lo,hi})  (f32 accum)
                asm("v_fma_mix_f32 %0, %1, %2, %0 op_sel:[0,0,0] op_sel_hi:[1,1,0]"
                    : "+v"(acc[qi][0]) : "v"(e), "v"(dat.x));
                asm("v_fma_mix_f32 %0, %1, %2, %0 op_sel:[0,1,0] op_sel_hi:[1,1,0]"
                    : "+v"(acc[qi][1]) : "v"(e), "v"(dat.x));
                asm("v_fma_mix_f32 %0, %1, %2, %0 op_sel:[0,0,0] op_sel_hi:[1,1,0]"
                    : "+v"(acc[qi][2]) : "v"(e), "v"(dat.y));
                asm("v_fma_mix_f32 %0, %1, %2, %0 op_sel:[0,1,0] op_sel_hi:[1,1,0]"
                    : "+v"(acc[qi][3]) : "v"(e), "v"(dat.y));
            }
            // bound the scheduler's hoisting window (r12 spill defense)
            __builtin_amdgcn_sched_barrier(0);
        }
    }

    // ---- quarter-wave reduce + transposed tile write (lanes 0-15) ----
    #pragma unroll
    for (int qi = 0; qi < 8; ++qi) {
        #pragma unroll
        for (int cc = 0; cc < 4; ++cc) {
            float v = acc[qi][cc];
            v += __shfl_xor(v, 16);
            v += __shfl_xor(v, 32);
            if (lane < 16)
                tile[wave * 8 + qi][4 * l15 + cc] = v;
        }
    }

    __syncthreads();

    // coalesced [F, N] store: each wave writes 8 channel-rows of 64 floats
    #pragma unroll
    for (int fi = 0; fi < 8; ++fi) {
        const int f = wave * 8 + fi;
        __builtin_nontemporal_store(tile[lane][f],
                                    &out[(size_t)f * N_Q + n0 + lane]);
    }
}

// ---- fallback: pure fp32 (no workspace) ----
__global__ __launch_bounds__(256) void knn_exp_f32(
    const float* __restrict__ dmat,
    const int*   __restrict__ imat,
    const float* __restrict__ alpha,
    const float* __restrict__ sigma,
    float*       __restrict__ out)
{
    __shared__ float tile[64][65];
    const int lane = threadIdx.x & 63;
    const int wave = threadIdx.x >> 6;
    const int n0   = blockIdx.x * 64;
    const float s = sigma[0];
    const float c = -0.5f / (s * s);

    for (int qi = 0; qi < 16; ++qi) {
        const int q = wave * 16 + qi;
        const int n = n0 + q;
        float wv = 0.0f;
        int   iv = 0;
        if (lane < 32) {
            wv = __expf(c * dmat[(size_t)n * K_NB + lane]);
        } else {
            iv = imat[(size_t)n * K_NB + (lane - 32)];
        }
        float acc = 0.0f;
        #pragma unroll
        for (int k = 0; k < K_NB; ++k) {
            const float wk = __int_as_float(
                __builtin_amdgcn_readlane(__float_as_int(wv), k));
            const int   ik = __builtin_amdgcn_readlane(iv, 32 + k);
            acc = fmaf(wk, alpha[(size_t)ik * F_CH + lane], acc);
        }
        tile[q][lane] = acc;
    }
    __syncthreads();
    #pragma unroll
    for (int fi = 0; fi < 16; ++fi) {
        const int f = wave * 16 + fi;
        out[(size_t)f * N_Q + n0 + lane] = tile[lane][f];
    }
}

extern "C" void kernel_launch(void* const* d_in, const int* in_sizes, int n_in,
                              void* d_out, int out_size, void* d_ws, size_t ws_size,
                              hipStream_t stream) {
    const float* dmat  = (const float*)d_in[0];
    const int*   imat  = (const int*)d_in[1];
    const float* alpha = (const float*)d_in[2];
    const float* sigma = (const float*)d_in[3];
    float* out = (float*)d_out;

    const size_t bytes_a16 = (size_t)M_ROWS * F_CH * sizeof(__half);  // 8 MiB

    if (ws_size >= bytes_a16) {
        __half* a16 = (__half*)d_ws;
        hipLaunchKernelGGL(cvt_alpha_f16, dim3(M_ROWS * F_CH / 8 / 256),
                           dim3(256), 0, stream, alpha, a16);
        hipLaunchKernelGGL(knn_exp_row4, dim3(N_Q / 64), dim3(512), 0,
                           stream, dmat, imat, a16, sigma, out);
    } else {
        hipLaunchKernelGGL(knn_exp_f32, dim3(N_Q / 64), dim3(256), 0, stream,
                           dmat, imat, alpha, sigma, out);
    }
}

// Round 17
// 58.038 us; speedup vs baseline: 1.2367x; 1.2367x over previous
//
#include <hip/hip_runtime.h>
#include <hip/hip_fp16.h>

// KnnExpansion: out[f, n] = sum_k alpha[i[n,k], f] * exp(-0.5 * d[n,k] / sigma^2)
// N=131072, K=32, M=65536, F=64.
//
// Structure (proven r15): fused in-register quartile partition + 4-phase
// L2-resident gather, 2 rows per dword gather (half-wave h -> entry 2t+h,
// 2 channels/lane), LDS-sourced entries, no readlane in consume.
// r16 (4 rows/instr) regressed -> 2 rows/instr is the request-amortization
// optimum. This round, two surgical deltas on r15:
//  (1) v_pk_fma_f16: both channels in ONE packed FMA (weight replicated
//      via op_sel_hi[0]=0; f16 accumulate, +~0.04 error, still << 0.4875)
//  (2) sched_barrier per query-PAIR -> 8 gathers in flight (2x MLP).

#define N_Q    131072
#define K_NB   32
#define F_CH   64
#define M_ROWS 65536

// ---- pre-pass: alpha f32 -> f16 (streaming, ~3us) ----
__global__ __launch_bounds__(256) void cvt_alpha_f16(
    const float* __restrict__ alpha, __half* __restrict__ a16)
{
    const int t = blockIdx.x * 256 + threadIdx.x;
    const float4 v0 = ((const float4*)alpha)[(size_t)t * 2 + 0];
    const float4 v1 = ((const float4*)alpha)[(size_t)t * 2 + 1];
    union { __half2 h2[4]; uint4 u; } pk;
    pk.h2[0] = __floats2half2_rn(v0.x, v0.y);
    pk.h2[1] = __floats2half2_rn(v0.z, v0.w);
    pk.h2[2] = __floats2half2_rn(v1.x, v1.y);
    pk.h2[3] = __floats2half2_rn(v1.z, v1.w);
    ((uint4*)a16)[t] = pk.u;
}

// ---- fused main: r15 structure + pk_fma + widened MLP window ----
__global__ __launch_bounds__(512) void knn_exp_pk(
    const float*  __restrict__ dmat,   // [N, 32]
    const int*    __restrict__ imat,   // [N, 32]
    const __half* __restrict__ a16,    // [65536, 64]
    const float*  __restrict__ sigma,  // [1]
    float*        __restrict__ out)    // [64, N]
{
    __shared__ float    tile[64][65];        // +1 pad
    __shared__ unsigned sortbuf[8][8][32];   // wave-local sort scratch

    const int lane = threadIdx.x & 63;
    const int wave = threadIdx.x >> 6;       // 8 waves x 8 queries
    const int n0   = blockIdx.x * 64;
    const bool hi  = (lane >= 32);
    const int  h   = lane >> 5;              // which row of the pair
    const int  l31 = lane & 31;
    const unsigned chan_off = (unsigned)l31 * 4u;  // 2 f16 channels per lane

    const float s = sigma[0];
    const float c = -0.5f / (s * s);

    // ---- batched prologue: 8 stream loads issued back-to-back (r10) ----
    const int nbase = n0 + wave * 8;
    const char* pbase = hi
        ? (const char*)&imat[(size_t)nbase * K_NB + (lane - 32)]
        : (const char*)&dmat[(size_t)nbase * K_NB + lane];
    unsigned raw[8];
    #pragma unroll
    for (int qi = 0; qi < 8; ++qi)
        raw[qi] = __builtin_nontemporal_load(
            (const unsigned*)(pbase + (size_t)qi * (K_NB * 4)));

    __builtin_amdgcn_sched_barrier(0);   // keep the batch; no sinking

    // ---- in-register quartile partition, pack (idx<<16 | f16(w)) ----
    #pragma unroll
    for (int qi = 0; qi < 8; ++qi) {
        const float wv = __expf(c * __uint_as_float(raw[qi])); // valid on lo
        const int   iv = (int)raw[qi];                         // valid on hi

        const unsigned hbits = (unsigned)__half_as_ushort(__float2half_rn(wv));
        const unsigned hb    = (unsigned)__shfl((int)hbits, lane & 31);

        const int quart = (iv >> 14) & 3;
        const unsigned long long m0 = __ballot(hi && quart == 0);
        const unsigned long long m1 = __ballot(hi && quart == 1);
        const unsigned long long m2 = __ballot(hi && quart == 2);
        const unsigned long long m3 = __ballot(hi && quart == 3);
        const int b1 = __popcll(m0);
        const int b2 = b1 + __popcll(m1);
        const int b3 = b2 + __popcll(m2);
        const unsigned long long mq =
            (quart == 0) ? m0 : (quart == 1) ? m1 : (quart == 2) ? m2 : m3;
        const int bq =
            (quart == 0) ? 0 : (quart == 1) ? b1 : (quart == 2) ? b2 : b3;
        const unsigned long long below = (1ull << lane) - 1ull;
        const int pos = bq + __popcll(mq & below);

        if (hi)
            sortbuf[wave][qi][pos] = ((unsigned)iv << 16) | (hb & 0xFFFFu);
    }
    // wave-local LDS RAW: same-wave ds ordering via lgkmcnt, no barrier.

    unsigned acc2[8];                        // packed f16x2 accumulators
    #pragma unroll
    for (int qi = 0; qi < 8; ++qi) acc2[qi] = 0u;

    // ---- 4-phase consume: phase p ~= quartile p (2 MiB L2 slice).
    // Group t: entries e=(p*8+2t+h); half-wave h gathers row(e) fully
    // (32 lanes x 4B = 128B); BOTH channels in one v_pk_fma_f16:
    //   lo += e.f16lo * dat.f16lo ; hi += e.f16lo * dat.f16hi
    // (op_sel_hi[0]=0 replicates the weight to the hi half).
    // sched_barrier per query-PAIR -> 8 loads in flight.
    #pragma unroll
    for (int p = 0; p < 4; ++p) {
        #pragma unroll
        for (int qp = 0; qp < 4; ++qp) {
            #pragma unroll
            for (int u = 0; u < 2; ++u) {
                const int qi = qp * 2 + u;
                #pragma unroll
                for (int t = 0; t < 4; ++t) {
                    const unsigned e = sortbuf[wave][qi][p * 8 + t * 2 + h];
                    const unsigned off = ((e >> 16) << 7) + chan_off;
                    const unsigned dat =
                        *(const unsigned*)((const char*)a16 + off);
                    asm("v_pk_fma_f16 %0, %1, %2, %0 op_sel:[0,0,0] op_sel_hi:[0,1,1]"
                        : "+v"(acc2[qi]) : "v"(e), "v"(dat));
                }
            }
            // bound the scheduler's hoisting window (r12 spill defense)
            __builtin_amdgcn_sched_barrier(0);
        }
    }

    // ---- unpack + cross-half reduce + transposed tile write ----
    #pragma unroll
    for (int qi = 0; qi < 8; ++qi) {
        union { unsigned u32; __half2 h2; } cv;
        cv.u32 = acc2[qi];
        const float2 f2 = __half22float2(cv.h2);
        const float sL = f2.x + __shfl_xor(f2.x, 32);
        const float sH = f2.y + __shfl_xor(f2.y, 32);
        if (!hi) {
            tile[wave * 8 + qi][2 * l31]     = sL;
            tile[wave * 8 + qi][2 * l31 + 1] = sH;
        }
    }

    __syncthreads();

    // coalesced [F, N] store: each wave writes 8 channel-rows of 64 floats
    #pragma unroll
    for (int fi = 0; fi < 8; ++fi) {
        const int f = wave * 8 + fi;
        __builtin_nontemporal_store(tile[lane][f],
                                    &out[(size_t)f * N_Q + n0 + lane]);
    }
}

// ---- fallback: pure fp32 (no workspace) ----
__global__ __launch_bounds__(256) void knn_exp_f32(
    const float* __restrict__ dmat,
    const int*   __restrict__ imat,
    const float* __restrict__ alpha,
    const float* __restrict__ sigma,
    float*       __restrict__ out)
{
    __shared__ float tile[64][65];
    const int lane = threadIdx.x & 63;
    const int wave = threadIdx.x >> 6;
    const int n0   = blockIdx.x * 64;
    const float s = sigma[0];
    const float c = -0.5f / (s * s);

    for (int qi = 0; qi < 16; ++qi) {
        const int q = wave * 16 + qi;
        const int n = n0 + q;
        float wv = 0.0f;
        int   iv = 0;
        if (lane < 32) {
            wv = __expf(c * dmat[(size_t)n * K_NB + lane]);
        } else {
            iv = imat[(size_t)n * K_NB + (lane - 32)];
        }
        float acc = 0.0f;
        #pragma unroll
        for (int k = 0; k < K_NB; ++k) {
            const float wk = __int_as_float(
                __builtin_amdgcn_readlane(__float_as_int(wv), k));
            const int   ik = __builtin_amdgcn_readlane(iv, 32 + k);
            acc = fmaf(wk, alpha[(size_t)ik * F_CH + lane], acc);
        }
        tile[q][lane] = acc;
    }
    __syncthreads();
    #pragma unroll
    for (int fi = 0; fi < 16; ++fi) {
        const int f = wave * 16 + fi;
        out[(size_t)f * N_Q + n0 + lane] = tile[lane][f];
    }
}

extern "C" void kernel_launch(void* const* d_in, const int* in_sizes, int n_in,
                              void* d_out, int out_size, void* d_ws, size_t ws_size,
                              hipStream_t stream) {
    const float* dmat  = (const float*)d_in[0];
    const int*   imat  = (const int*)d_in[1];
    const float* alpha = (const float*)d_in[2];
    const float* sigma = (const float*)d_in[3];
    float* out = (float*)d_out;

    const size_t bytes_a16 = (size_t)M_ROWS * F_CH * sizeof(__half);  // 8 MiB

    if (ws_size >= bytes_a16) {
        __half* a16 = (__half*)d_ws;
        hipLaunchKernelGGL(cvt_alpha_f16, dim3(M_ROWS * F_CH / 8 / 256),
                           dim3(256), 0, stream, alpha, a16);
        hipLaunchKernelGGL(knn_exp_pk, dim3(N_Q / 64), dim3(512), 0,
                           stream, dmat, imat, a16, sigma, out);
    } else {
        hipLaunchKernelGGL(knn_exp_f32, dim3(N_Q / 64), dim3(256), 0, stream,
                           dmat, imat, alpha, sigma, out);
    }
}

// Round 18
// 53.409 us; speedup vs baseline: 1.3439x; 1.0867x over previous
//
#include <hip/hip_runtime.h>
#include <hip/hip_fp16.h>

// KnnExpansion: out[f, n] = sum_k alpha[i[n,k], f] * exp(-0.5 * d[n,k] / sigma^2)
// N=131072, K=32, M=65536, F=64.
//
// Structure (proven r15, best main 46.3us): fused in-register quartile
// partition + 4-phase L2-resident gather, 2 rows per dword gather
// (half-wave h -> entry 2t+h, 2 ch/lane), LDS-sourced entries, fma_mix
// consume. This round: SAME consume, 256-thread blocks (4 waves x 8
// queries = 32 q/block, grid 4096, LDS 12.4KiB) -> 8 blocks/CU, 32
// waves = 100% static occupancy, finer dispatch granularity (16 rounds
// vs 2 -> smaller tail), phase-lockstep preserved.

#define N_Q    131072
#define K_NB   32
#define F_CH   64
#define M_ROWS 65536

// ---- pre-pass: alpha f32 -> f16 (streaming, ~3us) ----
__global__ __launch_bounds__(256) void cvt_alpha_f16(
    const float* __restrict__ alpha, __half* __restrict__ a16)
{
    const int t = blockIdx.x * 256 + threadIdx.x;
    const float4 v0 = ((const float4*)alpha)[(size_t)t * 2 + 0];
    const float4 v1 = ((const float4*)alpha)[(size_t)t * 2 + 1];
    union { __half2 h2[4]; uint4 u; } pk;
    pk.h2[0] = __floats2half2_rn(v0.x, v0.y);
    pk.h2[1] = __floats2half2_rn(v0.z, v0.w);
    pk.h2[2] = __floats2half2_rn(v1.x, v1.y);
    pk.h2[3] = __floats2half2_rn(v1.z, v1.w);
    ((uint4*)a16)[t] = pk.u;
}

// ---- fused main: r15 consume, 4-wave blocks for full occupancy ----
__global__ __launch_bounds__(256) void knn_exp_occ(
    const float*  __restrict__ dmat,   // [N, 32]
    const int*    __restrict__ imat,   // [N, 32]
    const __half* __restrict__ a16,    // [65536, 64]
    const float*  __restrict__ sigma,  // [1]
    float*        __restrict__ out)    // [64, N]
{
    __shared__ float    tile[32][65];        // +1 pad
    __shared__ unsigned sortbuf[4][8][32];   // wave-local sort scratch

    const int lane = threadIdx.x & 63;
    const int wave = threadIdx.x >> 6;       // 4 waves x 8 queries
    const int n0   = blockIdx.x * 32;        // 32 queries per block
    const bool hi  = (lane >= 32);
    const int  h   = lane >> 5;              // which row of the pair
    const int  l31 = lane & 31;
    const unsigned chan_off = (unsigned)l31 * 4u;  // 2 f16 channels per lane

    const float s = sigma[0];
    const float c = -0.5f / (s * s);

    // ---- batched prologue: 8 stream loads issued back-to-back (r10) ----
    const int nbase = n0 + wave * 8;
    const char* pbase = hi
        ? (const char*)&imat[(size_t)nbase * K_NB + (lane - 32)]
        : (const char*)&dmat[(size_t)nbase * K_NB + lane];
    unsigned raw[8];
    #pragma unroll
    for (int qi = 0; qi < 8; ++qi)
        raw[qi] = __builtin_nontemporal_load(
            (const unsigned*)(pbase + (size_t)qi * (K_NB * 4)));

    __builtin_amdgcn_sched_barrier(0);   // keep the batch; no sinking

    // ---- in-register quartile partition, pack (idx<<16 | f16(w)) ----
    #pragma unroll
    for (int qi = 0; qi < 8; ++qi) {
        const float wv = __expf(c * __uint_as_float(raw[qi])); // valid on lo
        const int   iv = (int)raw[qi];                         // valid on hi

        const unsigned hbits = (unsigned)__half_as_ushort(__float2half_rn(wv));
        const unsigned hb    = (unsigned)__shfl((int)hbits, lane & 31);

        const int quart = (iv >> 14) & 3;
        const unsigned long long m0 = __ballot(hi && quart == 0);
        const unsigned long long m1 = __ballot(hi && quart == 1);
        const unsigned long long m2 = __ballot(hi && quart == 2);
        const unsigned long long m3 = __ballot(hi && quart == 3);
        const int b1 = __popcll(m0);
        const int b2 = b1 + __popcll(m1);
        const int b3 = b2 + __popcll(m2);
        const unsigned long long mq =
            (quart == 0) ? m0 : (quart == 1) ? m1 : (quart == 2) ? m2 : m3;
        const int bq =
            (quart == 0) ? 0 : (quart == 1) ? b1 : (quart == 2) ? b2 : b3;
        const unsigned long long below = (1ull << lane) - 1ull;
        const int pos = bq + __popcll(mq & below);

        if (hi)
            sortbuf[wave][qi][pos] = ((unsigned)iv << 16) | (hb & 0xFFFFu);
    }
    // wave-local LDS RAW: same-wave ds ordering via lgkmcnt, no barrier.

    float accL[8], accH[8];
    #pragma unroll
    for (int qi = 0; qi < 8; ++qi) { accL[qi] = 0.0f; accH[qi] = 0.0f; }

    // ---- 4-phase consume (r15-proven): phase p ~= quartile p.
    // Group t: entries e=(p*8+2t+h); half-wave h gathers row(e) fully
    // (32 lanes x 4B = 128B); 2 channels/lane via fma_mix lo/hi.
    #pragma unroll
    for (int p = 0; p < 4; ++p) {
        #pragma unroll
        for (int qi = 0; qi < 8; ++qi) {
            #pragma unroll
            for (int t = 0; t < 4; ++t) {
                const unsigned e = sortbuf[wave][qi][p * 8 + t * 2 + h];
                const unsigned off = ((e >> 16) << 7) + chan_off;
                const unsigned dat = *(const unsigned*)((const char*)a16 + off);
                asm("v_fma_mix_f32 %0, %1, %2, %0 op_sel:[0,0,0] op_sel_hi:[1,1,0]"
                    : "+v"(accL[qi]) : "v"(e), "v"(dat));
                asm("v_fma_mix_f32 %0, %1, %2, %0 op_sel:[0,1,0] op_sel_hi:[1,1,0]"
                    : "+v"(accH[qi]) : "v"(e), "v"(dat));
            }
            // bound the scheduler's hoisting window (r12 spill defense)
            __builtin_amdgcn_sched_barrier(0);
        }
    }

    // ---- cross-half reduce + transposed tile write (lo half writes) ----
    #pragma unroll
    for (int qi = 0; qi < 8; ++qi) {
        const float sL = accL[qi] + __shfl_xor(accL[qi], 32);
        const float sH = accH[qi] + __shfl_xor(accH[qi], 32);
        if (!hi) {
            tile[wave * 8 + qi][2 * l31]     = sL;
            tile[wave * 8 + qi][2 * l31 + 1] = sH;
        }
    }

    __syncthreads();

    // coalesced [F, N] store: each wave writes 16 channel-rows of 32
    // floats; 2 rows per wave-instr (two 128B segments, all lanes used).
    #pragma unroll
    for (int fi = 0; fi < 8; ++fi) {
        const int f = wave * 16 + fi * 2 + h;
        __builtin_nontemporal_store(tile[l31][f],
                                    &out[(size_t)f * N_Q + n0 + l31]);
    }
}

// ---- fallback: pure fp32 (no workspace) ----
__global__ __launch_bounds__(256) void knn_exp_f32(
    const float* __restrict__ dmat,
    const int*   __restrict__ imat,
    const float* __restrict__ alpha,
    const float* __restrict__ sigma,
    float*       __restrict__ out)
{
    __shared__ float tile[64][65];
    const int lane = threadIdx.x & 63;
    const int wave = threadIdx.x >> 6;
    const int n0   = blockIdx.x * 64;
    const float s = sigma[0];
    const float c = -0.5f / (s * s);

    for (int qi = 0; qi < 16; ++qi) {
        const int q = wave * 16 + qi;
        const int n = n0 + q;
        float wv = 0.0f;
        int   iv = 0;
        if (lane < 32) {
            wv = __expf(c * dmat[(size_t)n * K_NB + lane]);
        } else {
            iv = imat[(size_t)n * K_NB + (lane - 32)];
        }
        float acc = 0.0f;
        #pragma unroll
        for (int k = 0; k < K_NB; ++k) {
            const float wk = __int_as_float(
                __builtin_amdgcn_readlane(__float_as_int(wv), k));
            const int   ik = __builtin_amdgcn_readlane(iv, 32 + k);
            acc = fmaf(wk, alpha[(size_t)ik * F_CH + lane], acc);
        }
        tile[q][lane] = acc;
    }
    __syncthreads();
    #pragma unroll
    for (int fi = 0; fi < 16; ++fi) {
        const int f = wave * 16 + fi;
        out[(size_t)f * N_Q + n0 + lane] = tile[lane][f];
    }
}

extern "C" void kernel_launch(void* const* d_in, const int* in_sizes, int n_in,
                              void* d_out, int out_size, void* d_ws, size_t ws_size,
                              hipStream_t stream) {
    const float* dmat  = (const float*)d_in[0];
    const int*   imat  = (const int*)d_in[1];
    const float* alpha = (const float*)d_in[2];
    const float* sigma = (const float*)d_in[3];
    float* out = (float*)d_out;

    const size_t bytes_a16 = (size_t)M_ROWS * F_CH * sizeof(__half);  // 8 MiB

    if (ws_size >= bytes_a16) {
        __half* a16 = (__half*)d_ws;
        hipLaunchKernelGGL(cvt_alpha_f16, dim3(M_ROWS * F_CH / 8 / 256),
                           dim3(256), 0, stream, alpha, a16);
        hipLaunchKernelGGL(knn_exp_occ, dim3(N_Q / 32), dim3(256), 0,
                           stream, dmat, imat, a16, sigma, out);
    } else {
        hipLaunchKernelGGL(knn_exp_f32, dim3(N_Q / 64), dim3(256), 0, stream,
                           dmat, imat, alpha, sigma, out);
    }
}